// Round 9
// baseline (32.446 us; speedup 1.0000x reference)
//
#include <hip/hip_runtime.h>

#define BB 16
#define CC 64
#define HH 64
#define WW 64
#define OO 128
#define ROWS 4                       // 2 output rows + 1 halo row each side
#define SLAB_DW (CC * ROWS * WW)     // 16384 dwords
#define LDS_BYTES (SLAB_DW * 4)      // 65536 B -> 2 blocks/CU

// Block: 512 threads = 8 waves, 2 blocks/CU. One wave: 16 o's over a 2-row
// strip; 64 lanes = 64 columns -> every tap is 64 consecutive dwords
// (2 lanes/bank = conflict-free; edge clamp = same-addr broadcast).
// Row pair per o via ds_read2_b32 (offsets 0 / 64 dwords).
// LDS slab: xs[c][rl][col], rl = clamped image rows r0-1 .. r0+2 (64 KB).
// Grid: 512 blocks = (b, 2-row strip); staging is pow-2 arithmetic only.
extern "C" __global__ __launch_bounds__(512, 4) void minimax_conv_kernel(
    const float* __restrict__ x, const float* __restrict__ w1,
    const float* __restrict__ w2, const int* __restrict__ conn,
    float* __restrict__ out)
{
    extern __shared__ float xs[];

    const int tid = threadIdx.x;
    const int bid = blockIdx.x;
    const int b  = bid >> 5;
    const int r0 = (bid & 31) * 2;

    const float* xb = x + (size_t)b * (CC * HH * WW);

    // ---- stage slab: 4096 float4 chunks = 8 rounds x 512 threads ----
    #pragma unroll
    for (int rnd = 0; rnd < 8; ++rnd) {
        const int f    = rnd * 512 + tid;     // 16-B chunk id, linear in LDS
        const int c    = f >> 6;              // 64 chunks per channel
        const int rem  = f & 63;
        const int rl   = rem >> 4;            // 0..3
        const int colq = (rem & 15) * 4;
        int rimg = r0 - 1 + rl;
        rimg = rimg < 0 ? 0 : (rimg > HH - 1 ? HH - 1 : rimg);
        const float4 v = *(const float4*)(xb + (c * HH + rimg) * WW + colq);
        *(float4*)(xs + f * 4) = v;
    }
    __syncthreads();

    const int lane = tid & 63;                                  // column
    const int wv   = __builtin_amdgcn_readfirstlane(tid >> 6);  // wave 0..7
    const int colm = (lane == 0)  ? 0  : lane - 1;
    const int colp = (lane == 63) ? 63 : lane + 1;

    float* outb = out + (((size_t)b * OO) * HH + r0) * WW + lane;

    // 16 o's per wave; 4 independent chains in flight
    #pragma unroll 4
    for (int oi = 0; oi < 16; ++oi) {
        const int o = wv * 16 + oi;           // wave-uniform

        float rA, rB;
        #pragma unroll
        for (int p = 0; p < 3; ++p) {
            float eA, eB;
            #pragma unroll
            for (int q = 0; q < 3; ++q) {
                const int t = p * 3 + q;
                const int v = conn[o * 9 + t];        // s_load (uniform)
                const int c = v / 9;                  // scalar magic-mul
                const int r9 = v - c * 9;
                const int i = r9 / 3;
                const int j = r9 - i * 3;
                const float w1v = w1[o * 9 + t];      // uniform

                const int col = (j == 0) ? colm : ((j == 1) ? lane : colp);
                // local rows i (output row r0) and i+1 (row r0+1)
                const float* pb = xs + c * (ROWS * WW) + i * WW + col;
                const float gA = pb[0];               // ds_read2_b32 pair
                const float gB = pb[WW];
                const float dA = fabsf(gA - w1v);
                const float dB = fabsf(gB - w1v);
                if (q == 0) { eA = dA; eB = dB; }
                else        { eA = fmaxf(eA, dA); eB = fmaxf(eB, dB); }
            }
            const float w2v = w2[o * 3 + p];          // uniform
            const float mA = fabsf(eA - w2v);
            const float mB = fabsf(eB - w2v);
            if (p == 0) { rA = mA; rB = mB; }
            else        { rA = fminf(rA, mA); rB = fminf(rB, mB); }
        }

        float* ob = outb + (size_t)o * (HH * WW);
        __builtin_nontemporal_store(rA, ob);
        __builtin_nontemporal_store(rB, ob + WW);
    }
}

extern "C" void kernel_launch(void* const* d_in, const int* in_sizes, int n_in,
                              void* d_out, int out_size, void* d_ws, size_t ws_size,
                              hipStream_t stream) {
    const float* x    = (const float*)d_in[0];
    const float* w1   = (const float*)d_in[1];
    const float* w2   = (const float*)d_in[2];
    const int*   conn = (const int*)d_in[3];
    float* out = (float*)d_out;

    hipFuncSetAttribute((const void*)minimax_conv_kernel,
                        hipFuncAttributeMaxDynamicSharedMemorySize, LDS_BYTES);

    const int blocks = BB * 32;   // (b, 2-row strip) = 512 blocks, 2/CU
    minimax_conv_kernel<<<blocks, 512, LDS_BYTES, stream>>>(x, w1, w2, conn, out);
}